// Round 6
// baseline (322.281 us; speedup 1.0000x reference)
//
#include <hip/hip_runtime.h>
#include <hip/hip_bf16.h>

// ModulatedConv2d: B=16, C_in=C_out=128, H=W=128, K=3, S=512. fp32 I/O.
// Compute: bf16 MFMA (16x16x32), fp32 accumulate.
//
// R10: 18-phase pipelined schedule (T3+T4+T5), no extra workspace.
//  - k_conv: h-pair blocks, 512 thr / 8 waves (2co x 2h x 2w), BM=128 x BN=256.
//    Xs: 4 image rows (128 KB) cvt-staged ONCE in prologue (R5-proven path).
//    Ws: 2 x 16 KB half-tap double-buffer, global_load_lds from fragment-order
//    wsW; DMA for phase p+1 issued at start of phase p (1-phase-deep pipeline,
//    covers L2/HBM latency under 32 MFMA + 16 ds_read).
//    18 phases, ONE __syncthreads each (drain is cheap: DMAs issued a full
//    phase earlier). LDS = 160 KB exactly -> 1 block/CU, 8 waves.
//  - A shared via LDS: 16 KB/block-phase vs R6's 4x-redundant per-wave loads.
//  - Accumulation order unchanged (kh,kw,ks) -> bitwise-identical output.
//  - Workspace: 8 KB + 4.72 MB (proven size), no x_t prepass.

#define Bn 16
#define Cc 128
#define HW 128
#define Sv 512

typedef __bf16 bf16x8 __attribute__((ext_vector_type(8)));
typedef float f32x4 __attribute__((ext_vector_type(4)));
typedef unsigned short ushort8 __attribute__((ext_vector_type(8)));

static __device__ __forceinline__ unsigned short bf16bits(float f) {
    return __builtin_bit_cast(unsigned short, __float2bfloat16(f));
}

static __device__ __forceinline__ void gl_lds16(const void* g, void* l) {
    __builtin_amdgcn_global_load_lds(
        (const __attribute__((address_space(1))) unsigned int*)g,
        (__attribute__((address_space(3))) unsigned int*)l, 16, 0, 0);
}

// ---------------- kernel 1: s[b][ci] = style[b,:] . mod_w[ci,:] + mod_b[ci]
__global__ __launch_bounds__(64) void k_style(const float* __restrict__ style,
                                              const float* __restrict__ mod_w,
                                              const float* __restrict__ mod_b,
                                              float* __restrict__ s_out) {
    int b = blockIdx.x >> 7, ci = blockIdx.x & 127;
    int lane = threadIdx.x;
    const float* st = style + (size_t)b * Sv;
    const float* mw = mod_w + (size_t)ci * Sv;
    float acc = 0.f;
#pragma unroll
    for (int k = 0; k < Sv; k += 64)
        acc += st[k + lane] * mw[k + lane];
#pragma unroll
    for (int off = 32; off > 0; off >>= 1)
        acc += __shfl_down(acc, off, 64);
    if (lane == 0) s_out[b * Cc + ci] = acc + mod_b[ci];
}

// ---------------- kernel 2: modulate + demodulate, store bf16 MFMA-FRAGMENT order
//   wsW[((b*9 + j)*32 + frag)*512 + lane*8 + e]
//   frag = (co>>6)*16 + ((co>>4)&3)*4 + (ci>>5);  lane = ((ci>>3)&3)*16 + (co&15);
//   e = ci&7   -> lane l's bf16x8 at (frag,l) = A[co=m2*64+mi*16+(l&15)][k=(ks*4+(l>>4))*8..]
__global__ __launch_bounds__(128) void k_mod(const float* __restrict__ weight,
                                             const float* __restrict__ s,
                                             __hip_bfloat16* __restrict__ wsW) {
    int b = blockIdx.x >> 7;
    int co = blockIdx.x & 127;
    int ci = threadIdx.x;
    float sv = s[b * Cc + ci];
    const float* wp = weight + ((size_t)co * Cc + ci) * 9;
    float wv[9];
    float ss = 0.f;
#pragma unroll
    for (int j = 0; j < 9; j++) {
        wv[j] = wp[j] * sv;
        ss += wv[j] * wv[j];
    }
    __shared__ float red[128];
    __shared__ __align__(16) __bf16 wo[9 * 128];
    red[ci] = ss;
    __syncthreads();
    for (int s2 = 64; s2 > 0; s2 >>= 1) {
        if (ci < s2) red[ci] += red[ci + s2];
        __syncthreads();
    }
    float dec = rsqrtf(red[0] + 1e-8f);
#pragma unroll
    for (int j = 0; j < 9; j++)
        wo[j * 128 + ci] = __float2bfloat16(wv[j] * dec);
    __syncthreads();
    int fragbase = ((co >> 6) << 4) | (((co >> 4) & 3) << 2);
#pragma unroll
    for (int it = 0; it < 2; it++) {
        int c = it * 128 + ci;
        if (c < 144) {
            int j = c >> 4, g = c & 15;
            bf16x8 chunk = *(const bf16x8*)(&wo[j * 128 + g * 8]);
            size_t off = (((size_t)b * 9 + j) * 32 + fragbase + (g >> 2)) * 512 +
                         (size_t)(((g & 3) << 4) | (co & 15)) * 8;
            *(bf16x8*)(wsW + off) = chunk;
        }
    }
}

// ---------------- kernel 3: implicit-GEMM conv, 18-phase pipelined
// Xs[j][w][slot]: slab j = image row h0-1+j (OOB rows zero); slot sg holds
// ci-group g = sg ^ (w&7). Ws: half-tap fragment buffer, slot = m2*8+mi*2+jj.
__global__ __launch_bounds__(512, 2) void k_conv(const float* __restrict__ x,
                                                 const __hip_bfloat16* __restrict__ wsW,
                                                 float* __restrict__ out) {
    __shared__ __align__(16) __bf16 Xs[4 * 128 * 128];  // 128 KB
    __shared__ __align__(16) __bf16 Ws[2][16 * 512];    // 2 x 16 KB -> 160 KB total

    int bx0 = blockIdx.x;
    int bx = (bx0 & 7) * 128 + (bx0 >> 3);  // XCD swizzle, bijective (1024%8==0)
    int b = bx >> 6;
    int h0 = (bx & 63) << 1;

    int t = threadIdx.x;
    int lane = t & 63;
    int wv = t >> 6;            // 0..7
    int wave_m = wv >> 2;       // co half
    int wave_n = wv & 3;        // n quarter
    int hsub = wave_n >> 1;     // h row within pair
    int wbase = (wave_n & 1) << 6;
    int l15 = lane & 15, quad = lane >> 4;

    f32x4 acc[4][4] = {};

    const float* xb = x + (size_t)b * (Cc * HW * HW);
    const __hip_bfloat16* wtb = wsW + (size_t)b * 9 * (32 * 512) + (size_t)lane * 8;

    // ---- issue Ws half-tap 0 DMA first (lands under the Xs staging) ----
#pragma unroll
    for (int q = 0; q < 2; q++) {
        int fb = wv * 2 + q;
        int f = ((fb >> 3) << 4) + (((fb >> 1) & 3) << 2) + (fb & 1);  // tap0 ht0
        gl_lds16(wtb + (size_t)f * 512, &Ws[0][fb * 512]);
    }

    // ---- stage 4 image rows (h0-1 .. h0+2) ONCE (R5-proven path) ----
    // item id: w = id&127 (lanes->consecutive w: coalesced), g = id>>7
#pragma unroll
    for (int j = 0; j < 4; j++) {
        int hp = h0 - 1 + j;
        bool ok = (unsigned)hp < (unsigned)HW;  // block-uniform; OOB -> zeros
        const float* xr = xb + (size_t)hp * HW;
#pragma unroll
        for (int c = 0; c < 4; c++) {
            int id = c * 512 + t;
            int w = id & 127;
            int g = id >> 7;  // ci-group 0..15
            ushort8 pk = {};
            if (ok) {
                const float* p = xr + (size_t)g * 8 * (HW * HW) + w;
#pragma unroll
                for (int e = 0; e < 8; e++)
                    pk[e] = bf16bits(p[(size_t)e * (HW * HW)]);
            }
            *(bf16x8*)(&Xs[j * 16384 + w * 128 + ((g ^ (w & 7)) << 3)]) =
                __builtin_bit_cast(bf16x8, pk);
        }
    }
    __syncthreads();  // Xs + Ws[0] visible (drains vmcnt/lgkmcnt)

    // ---- 18 phases: tap = p>>1, half-tap ht = p&1, buffer = p&1 ----
#pragma unroll
    for (int p = 0; p < 18; p++) {
        const int tap = p >> 1, ht = p & 1, buf = p & 1;
        const int kh = tap / 3, kw = tap % 3;
        // issue next half-tap DMA into the other buffer (1-phase-deep pipeline)
        if (p < 17) {
            const int ntap = (p + 1) >> 1, nht = (p + 1) & 1, nbuf = (p + 1) & 1;
#pragma unroll
            for (int q = 0; q < 2; q++) {
                int fb = wv * 2 + q;
                int f = ((fb >> 3) << 4) + (((fb >> 1) & 3) << 2) + 2 * nht + (fb & 1);
                gl_lds16(wtb + ((size_t)ntap * 32 + f) * 512, &Ws[nbuf][fb * 512]);
            }
        }
        const int jimg = hsub + kh;  // image slab for this wave's h row
#pragma unroll
        for (int jj = 0; jj < 2; jj++) {
            const int ks = ht * 2 + jj;
            int kg = ks * 4 + quad;  // k0 = kg*8
            bf16x8 a[4], bb[4];
#pragma unroll
            for (int mi = 0; mi < 4; mi++)
                a[mi] = *(const bf16x8*)(
                    &Ws[buf][(wave_m * 8 + mi * 2 + jj) * 512 + lane * 8]);
#pragma unroll
            for (int ni = 0; ni < 4; ni++) {
                int xc = wbase + ni * 16 + l15 + kw - 1;  // x-col, -1..128
                int xcc = min(127, max(0, xc));
                bf16x8 v = *(const bf16x8*)(
                    &Xs[jimg * 16384 + xcc * 128 + ((kg ^ (xcc & 7)) << 3)]);
                if ((kw == 0 && ni == 0) || (kw == 2 && ni == 3)) {
                    if (xc != xcc) v = (bf16x8){};  // w-edge zero
                }
                bb[ni] = v;
            }
            __builtin_amdgcn_s_setprio(1);
#pragma unroll
            for (int mi = 0; mi < 4; mi++)
#pragma unroll
                for (int ni = 0; ni < 4; ni++)
                    acc[mi][ni] = __builtin_amdgcn_mfma_f32_16x16x32_bf16(
                        a[mi], bb[ni], acc[mi][ni], 0, 0, 0);
            __builtin_amdgcn_s_setprio(0);
        }
        __syncthreads();  // next buffer ready; my DMAs issued a full phase ago
    }

    // epilogue: co = wave_m*64 + mi*16 + quad*4 + r; w = wbase + ni*16 + l15
    int h = h0 + hsub;
    float* ob = out + (size_t)b * (Cc * HW * HW) + (size_t)h * HW;
#pragma unroll
    for (int mi = 0; mi < 4; mi++) {
#pragma unroll
        for (int ni = 0; ni < 4; ni++) {
            int w = wbase + ni * 16 + l15;
#pragma unroll
            for (int r = 0; r < 4; r++) {
                int co = wave_m * 64 + mi * 16 + quad * 4 + r;
                ob[(size_t)co * (HW * HW) + w] = acc[mi][ni][r];
            }
        }
    }
}

extern "C" void kernel_launch(void* const* d_in, const int* in_sizes, int n_in,
                              void* d_out, int out_size, void* d_ws, size_t ws_size,
                              hipStream_t stream) {
    const float* x      = (const float*)d_in[0];
    const float* style  = (const float*)d_in[1];
    const float* weight = (const float*)d_in[2];
    const float* mod_w  = (const float*)d_in[3];
    const float* mod_b  = (const float*)d_in[4];
    float* out = (float*)d_out;

    // workspace: s (fp32, 8KB) | wsW (bf16 fragment-order, 4.72MB)
    float* s_ws = (float*)d_ws;
    __hip_bfloat16* wsW = (__hip_bfloat16*)((char*)d_ws + 8192);

    k_style<<<Bn * Cc, 64, 0, stream>>>(style, mod_w, mod_b, s_ws);
    k_mod<<<Bn * Cc, 128, 0, stream>>>(weight, s_ws, wsW);
    k_conv<<<Bn * (HW / 2), 512, 0, stream>>>(x, wsW, out);
}